// Round 3
// baseline (21.307 us; speedup 1.0000x reference)
//
#include <hip/hip_runtime.h>
#include <hip/hip_bf16.h>

#define SUB 4           // threads cooperating per probe
#define ROWF 28         // floats per packed atom row (112 B, 16B-aligned)

// slot -> orbital map (RAD_IDX) and SH constant folds
__device__ __constant__ int   kRadIdx[23] = {0,1,2,3, 4,4,4, 5,5,5, 6,6,6, 7,7,7,7,7, 8,8,8,8,8};

// ---------------- prepass: pack per-atom data into d_ws ----------------
// row = [ax',ay',az', c'0..c'22, 0,0] with coords reordered [1,2,0] and
// scaled to Bohr; c' = c * exp(lognorm[orb]) * sh_const[slot].
__global__ __launch_bounds__(256) void pack_kernel(
    const float* __restrict__ atom,    // [Atot,3]
    const float* __restrict__ coeffs,  // [Atot,23]
    const float* __restrict__ expos,   // [9]
    float* __restrict__ ws,            // [Atot, ROWF]
    int atot)
{
    const int a = blockIdx.x * blockDim.x + threadIdx.x;
    if (a >= atot) return;

    const float gl[3]  = {-0.12078223763524522f, 0.28468287047291918f, 1.2009736023470742f};
    const int   lsq[9] = {0,0,0,0,1,1,1,2,2};
    const float S3 = 1.7320508075688772f;
    const float shf[23] = {1,1,1,1, 1,1,1, 1,1,1, 1,1,1,
                           S3, S3, 1.0f, S3, 0.5f*S3,
                           S3, S3, 1.0f, S3, 0.5f*S3};
    float en[9];
#pragma unroll
    for (int k = 0; k < 9; ++k) {
        float e  = expos[k];
        float pw = (float)lsq[k] + 1.5f;
        float ln = 0.5f * (pw * __logf(2.0f * e) + 0.69314718055994531f - gl[lsq[k]]);
        en[k] = __expf(ln);
    }
    const float IB = 1.8897259885789233f;  // 1/0.529177249
    float* row = ws + a * ROWF;
    row[0] = atom[a * 3 + 1] * IB;
    row[1] = atom[a * 3 + 2] * IB;
    row[2] = atom[a * 3 + 0] * IB;
#pragma unroll
    for (int s = 0; s < 23; ++s)
        row[3 + s] = coeffs[a * 23 + s] * en[kRadIdx[s]] * shf[s];
    row[26] = 0.0f; row[27] = 0.0f;
}

// ---------------- main kernel ----------------
__global__ __launch_bounds__(256) void gto_kernel(
    const float* __restrict__ probe,   // [Ptot,3] (Angstrom)
    const int* __restrict__ n_probes,  // [B]
    const int* __restrict__ n_atoms,   // [B]
    const float* __restrict__ expos,   // [9]
    const float* __restrict__ ws,      // [Atot, ROWF] packed
    float* __restrict__ out,           // [Ptot]
    int bsz, int ptot)
{
    const int t = blockIdx.x * blockDim.x + threadIdx.x;
    const int p = t / SUB;
    const int sub = t % SUB;
    if (p >= ptot) return;

    // batch of this probe (ragged-general)
    int poff = 0, aoff = 0, na = 0;
    for (int b = 0; b < bsz; ++b) {
        int np = n_probes[b];
        int nb = n_atoms[b];
        if (p < poff + np) { na = nb; break; }
        poff += np; aoff += nb;
    }

    // exp2-scaled exponents (once per thread)
    const float NL2 = -1.4426950408889634f;  // -1/ln2
    float e2n[9];
#pragma unroll
    for (int k = 0; k < 9; ++k) e2n[k] = expos[k] * NL2;

    const float IB = 1.8897259885789233f;
    const float pxs = probe[p * 3 + 1] * IB;   // reorder [1,2,0], Ang->Bohr
    const float pys = probe[p * 3 + 2] * IB;
    const float pzs = probe[p * 3 + 0] * IB;

    float acc = 0.0f;
    for (int a = sub; a < na; a += SUB) {
        const float4* row = (const float4*)(ws + (size_t)(aoff + a) * ROWF);
        const float4 f0 = row[0], f1 = row[1], f2 = row[2], f3 = row[3];
        const float4 f4 = row[4], f5 = row[5], f6 = row[6];

        const float x = pxs - f0.x;
        const float y = pys - f0.y;
        const float z = pzs - f0.z;
        const float xx = x * x, yy = y * y, zz = z * z;
        const float r2 = xx + yy + zz;     // eps^2 + 2*eps*r term is ~1e-7, negligible

        float er[9];
#pragma unroll
        for (int k = 0; k < 9; ++k) er[k] = __builtin_amdgcn_exp2f(e2n[k] * r2);

        // l=2 polynomial basis (SH constants folded into coeffs)
        const float q1 = x * z;
        const float q2 = x * y;
        const float q4 = y * z;
        const float q3 = yy - 0.5f * (xx + zz);
        const float q5 = zz - xx;

        float pp;
        pp  = er[0] * f0.w + er[1] * f1.x + er[2] * f1.y + er[3] * f1.z;
        pp += er[4] * (x * f1.w + y * f2.x + z * f2.y);
        pp += er[5] * (x * f2.z + y * f2.w + z * f3.x);
        pp += er[6] * (x * f3.y + y * f3.z + z * f3.w);
        pp += er[7] * (q1 * f4.x + q2 * f4.y + q3 * f4.z + q4 * f4.w + q5 * f5.x);
        pp += er[8] * (q1 * f5.y + q2 * f5.z + q3 * f5.w + q4 * f6.x + q5 * f6.y);
        acc += pp;
    }

#pragma unroll
    for (int ofs = SUB / 2; ofs > 0; ofs >>= 1)
        acc += __shfl_xor(acc, ofs, 64);

    if (sub == 0) out[p] = acc;
}

extern "C" void kernel_launch(void* const* d_in, const int* in_sizes, int n_in,
                              void* d_out, int out_size, void* d_ws, size_t ws_size,
                              hipStream_t stream) {
    const float* probe  = (const float*)d_in[0];
    const float* atom   = (const float*)d_in[1];
    const int*   n_prb  = (const int*)d_in[2];
    const int*   n_atm  = (const int*)d_in[3];
    const float* coeffs = (const float*)d_in[4];
    const float* expos  = (const float*)d_in[5];
    float*       out    = (float*)d_out;
    float*       ws     = (float*)d_ws;

    const int bsz  = in_sizes[2];
    const int atot = in_sizes[1] / 3;
    const int ptot = out_size;

    pack_kernel<<<(atot + 255) / 256, 256, 0, stream>>>(atom, coeffs, expos, ws, atot);

    const int threads = ptot * SUB;
    const int block = 256;
    const int grid = (threads + block - 1) / block;
    gto_kernel<<<grid, block, 0, stream>>>(probe, n_prb, n_atm, expos, ws, out, bsz, ptot);
}

// Round 4
// 16.248 us; speedup vs baseline: 1.3114x; 1.3114x over previous
//
#include <hip/hip_runtime.h>

#define SUB 4  // threads cooperating per probe (consecutive lanes)

typedef float f4u __attribute__((ext_vector_type(4), aligned(4)));
typedef float f2u __attribute__((ext_vector_type(2), aligned(4)));

__global__ __launch_bounds__(256) void gto_kernel(
    const float* __restrict__ probe,   // [Ptot,3] (Angstrom)
    const float* __restrict__ atom,    // [Atot,3]
    const int* __restrict__ n_probes,  // [B]
    const int* __restrict__ n_atoms,   // [B]
    const float* __restrict__ coeffs,  // [Atot,23]
    const float* __restrict__ expos,   // [9]
    float* __restrict__ out,           // [Ptot]
    int bsz, int ptot)
{
    const int t = blockIdx.x * blockDim.x + threadIdx.x;
    int p = t / SUB;
    const int sub = t & (SUB - 1);
    const bool alive = (p < ptot);
    if (!alive) p = ptot - 1;          // clamp; OOB lane-groups stay self-contained
    const int lane = threadIdx.x & 63;

    // ---- batch lookup: 2 coalesced loads + wave-register scan (no serial load chain) ----
    int aoff = 0, na = 0;
    if (bsz <= 64) {
        int npl = 0, nal = 0;
        if (lane < bsz) { npl = n_probes[lane]; nal = n_atoms[lane]; }
        int cp = 0, ca = 0;
        for (int b = 0; b < bsz; ++b) {
            const int np_b = __shfl(npl, b, 64);
            const int na_b = __shfl(nal, b, 64);
            if (p >= cp && p < cp + np_b) { aoff = ca; na = na_b; }
            cp += np_b; ca += na_b;
        }
    } else {  // generic fallback (not hit for this shape)
        int cp = 0, ca = 0;
        for (int b = 0; b < bsz; ++b) {
            const int np_b = n_probes[b];
            const int na_b = n_atoms[b];
            if (p >= cp && p < cp + np_b) { aoff = ca; na = na_b; }
            cp += np_b; ca += na_b;
        }
    }

    // ---- per-orbital constants: lognorm folded into exp2 argument ----
    // lnb2[k] = log2(exp(lognorm_k)) = 0.5*(pw*log2(2e) + 1 - gammaln(pw)/ln2)
    const float gl2[3]  = {-0.17425190f, 0.41071060f, 1.73263870f};  // gammaln(l+1.5)/ln2
    const int   lsq[9]  = {0,0,0,0,1,1,1,2,2};
    const float NL2 = -1.4426950408889634f;  // -1/ln2
    float e2n[9], lb2[9];
#pragma unroll
    for (int k = 0; k < 9; ++k) {
        const float e  = expos[k];
        const float pw = (float)lsq[k] + 1.5f;
        e2n[k] = e * NL2;
        lb2[k] = 0.5f * (pw * __log2f(2.0f * e) + 1.0f - gl2[lsq[k]]);
    }

    const float IB  = 1.8897259885789233f;   // 1/0.529177249
    const float S3  = 1.7320508075688772f;
    const float HS3 = 0.8660254037844386f;

    // probe coords: reorder [1,2,0], Ang -> Bohr (once)
    const float pxs = probe[p * 3 + 1] * IB;
    const float pys = probe[p * 3 + 2] * IB;
    const float pzs = probe[p * 3 + 0] * IB;

    float acc = 0.0f;
#pragma unroll 2
    for (int a = sub; a < na; a += SUB) {
        const size_t ai = (size_t)(aoff + a);
        const float* ar = atom + ai * 3;
        const float a0 = ar[0], a1 = ar[1], a2 = ar[2];
        const float* cr = coeffs + ai * 23;
        const f4u c0 = *(const f4u*)(cr);
        const f4u c4 = *(const f4u*)(cr + 4);
        const f4u c8 = *(const f4u*)(cr + 8);
        const f4u cc = *(const f4u*)(cr + 12);
        const f4u cg = *(const f4u*)(cr + 16);
        const f2u ck = *(const f2u*)(cr + 20);
        const float cm = cr[22];

        const float x = __builtin_fmaf(-IB, a1, pxs);
        const float y = __builtin_fmaf(-IB, a2, pys);
        const float z = __builtin_fmaf(-IB, a0, pzs);
        const float xx = x * x, yy = y * y, zz = z * z;
        const float r2 = xx + yy + zz;   // (r+eps)^l factors cancel exactly; eps in exp arg ~3e-6 rel

        float er[9];
#pragma unroll
        for (int k = 0; k < 9; ++k)
            er[k] = __builtin_amdgcn_exp2f(__builtin_fmaf(e2n[k], r2, lb2[k]));

        // l=0
        float s = er[0] * c0.x;
        s = __builtin_fmaf(er[1], c0.y, s);
        s = __builtin_fmaf(er[2], c0.z, s);
        s = __builtin_fmaf(er[3], c0.w, s);
        // l=1 (r * unit-vec == plain x,y,z)
        float d;
        d = __builtin_fmaf(x, c4.x, __builtin_fmaf(y, c4.y, z * c4.z));
        s = __builtin_fmaf(er[4], d, s);
        d = __builtin_fmaf(x, c4.w, __builtin_fmaf(y, c8.x, z * c8.y));
        s = __builtin_fmaf(er[5], d, s);
        d = __builtin_fmaf(x, c8.z, __builtin_fmaf(y, c8.w, z * cc.x));
        s = __builtin_fmaf(er[6], d, s);
        // l=2 monomial basis with SH constants folded (shared by both orbitals)
        const float u1 = S3 * (x * z);
        const float u2 = S3 * (x * y);
        const float q3 = __builtin_fmaf(-0.5f, xx + zz, yy);
        const float u4 = S3 * (y * z);
        const float u5 = HS3 * (zz - xx);
        d = __builtin_fmaf(u1, cc.y, __builtin_fmaf(u2, cc.z,
            __builtin_fmaf(q3, cc.w, __builtin_fmaf(u4, cg.x, u5 * cg.y))));
        s = __builtin_fmaf(er[7], d, s);
        d = __builtin_fmaf(u1, cg.z, __builtin_fmaf(u2, cg.w,
            __builtin_fmaf(q3, ck.x, __builtin_fmaf(u4, ck.y, u5 * cm))));
        s = __builtin_fmaf(er[8], d, s);
        acc += s;
    }

    // reduce across the SUB consecutive lanes of this probe
    acc += __shfl_xor(acc, 1, 64);
    acc += __shfl_xor(acc, 2, 64);

    if (alive && sub == 0) out[p] = acc;
}

extern "C" void kernel_launch(void* const* d_in, const int* in_sizes, int n_in,
                              void* d_out, int out_size, void* d_ws, size_t ws_size,
                              hipStream_t stream) {
    const float* probe  = (const float*)d_in[0];
    const float* atom   = (const float*)d_in[1];
    const int*   n_prb  = (const int*)d_in[2];
    const int*   n_atm  = (const int*)d_in[3];
    const float* coeffs = (const float*)d_in[4];
    const float* expos  = (const float*)d_in[5];
    float*       out    = (float*)d_out;

    const int bsz  = in_sizes[2];
    const int ptot = out_size;

    const long threads = (long)ptot * SUB;
    const int block = 256;
    const int grid = (int)((threads + block - 1) / block);
    gto_kernel<<<grid, block, 0, stream>>>(probe, atom, n_prb, n_atm, coeffs, expos, out, bsz, ptot);
}

// Round 5
// 15.922 us; speedup vs baseline: 1.3382x; 1.0204x over previous
//
#include <hip/hip_runtime.h>

#define SUB 8  // threads cooperating per probe (consecutive lanes)

typedef float f4u __attribute__((ext_vector_type(4), aligned(4)));
typedef float f2u __attribute__((ext_vector_type(2), aligned(4)));

__global__ __launch_bounds__(256) void gto_kernel(
    const float* __restrict__ probe,   // [Ptot,3] (Angstrom)
    const float* __restrict__ atom,    // [Atot,3]
    const int* __restrict__ n_probes,  // [B]
    const int* __restrict__ n_atoms,   // [B]
    const float* __restrict__ coeffs,  // [Atot,23]
    const float* __restrict__ expos,   // [9]
    float* __restrict__ out,           // [Ptot]
    int bsz, int ptot)
{
    const int t = blockIdx.x * blockDim.x + threadIdx.x;
    int p = t / SUB;
    const int sub = t & (SUB - 1);
    const bool alive = (p < ptot);
    if (!alive) p = ptot - 1;          // clamp; OOB lane-groups stay self-contained
    const int lane = threadIdx.x & 63;

    // ---- batch lookup: 2 coalesced loads + wave-register scan (no serial load chain) ----
    int aoff = 0, na = 0;
    if (bsz <= 64) {
        int npl = 0, nal = 0;
        if (lane < bsz) { npl = n_probes[lane]; nal = n_atoms[lane]; }
        int cp = 0, ca = 0;
        for (int b = 0; b < bsz; ++b) {
            const int np_b = __shfl(npl, b, 64);
            const int na_b = __shfl(nal, b, 64);
            if (p >= cp && p < cp + np_b) { aoff = ca; na = na_b; }
            cp += np_b; ca += na_b;
        }
    } else {  // generic fallback (not hit for this shape)
        int cp = 0, ca = 0;
        for (int b = 0; b < bsz; ++b) {
            const int np_b = n_probes[b];
            const int na_b = n_atoms[b];
            if (p >= cp && p < cp + np_b) { aoff = ca; na = na_b; }
            cp += np_b; ca += na_b;
        }
    }

    // ---- per-orbital constants: lognorm folded into exp2 argument ----
    // lb2[k] = log2(exp(lognorm_k)) = 0.5*(pw*log2(2e) + 1 - gammaln(pw)/ln2)
    const float gl2[3]  = {-0.17425190f, 0.41071060f, 1.73263870f};  // gammaln(l+1.5)/ln2
    const int   lsq[9]  = {0,0,0,0,1,1,1,2,2};
    const float NL2 = -1.4426950408889634f;  // -1/ln2
    float e2n[9], lb2[9];
#pragma unroll
    for (int k = 0; k < 9; ++k) {
        const float e  = expos[k];
        const float pw = (float)lsq[k] + 1.5f;
        e2n[k] = e * NL2;
        lb2[k] = 0.5f * (pw * __log2f(2.0f * e) + 1.0f - gl2[lsq[k]]);
    }

    const float IB  = 1.8897259885789233f;   // 1/0.529177249
    const float S3  = 1.7320508075688772f;
    const float HS3 = 0.8660254037844386f;

    // probe coords: reorder [1,2,0], Ang -> Bohr (once)
    const float pxs = probe[p * 3 + 1] * IB;
    const float pys = probe[p * 3 + 2] * IB;
    const float pzs = probe[p * 3 + 0] * IB;

    float acc = 0.0f;
#pragma unroll 2
    for (int a = sub; a < na; a += SUB) {
        const size_t ai = (size_t)(aoff + a);
        const float* ar = atom + ai * 3;
        const f2u a01 = *(const f2u*)(ar);
        const float a2 = ar[2];
        const float* cr = coeffs + ai * 23;
        const f4u c0 = *(const f4u*)(cr);
        const f4u c4 = *(const f4u*)(cr + 4);
        const f4u c8 = *(const f4u*)(cr + 8);
        const f4u cc = *(const f4u*)(cr + 12);
        const f4u cg = *(const f4u*)(cr + 16);
        const f2u ck = *(const f2u*)(cr + 20);
        const float cm = cr[22];

        const float x = __builtin_fmaf(-IB, a01.y, pxs);
        const float y = __builtin_fmaf(-IB, a2,    pys);
        const float z = __builtin_fmaf(-IB, a01.x, pzs);
        const float xx = x * x, yy = y * y, zz = z * z;
        const float r2 = xx + yy + zz;   // (r+eps)^l factors cancel exactly; eps in exp arg ~3e-6 rel

        float er[9];
#pragma unroll
        for (int k = 0; k < 9; ++k)
            er[k] = __builtin_amdgcn_exp2f(__builtin_fmaf(e2n[k], r2, lb2[k]));

        // l=0
        float s = er[0] * c0.x;
        s = __builtin_fmaf(er[1], c0.y, s);
        s = __builtin_fmaf(er[2], c0.z, s);
        s = __builtin_fmaf(er[3], c0.w, s);
        // l=1 (r * unit-vec == plain x,y,z)
        float d;
        d = __builtin_fmaf(x, c4.x, __builtin_fmaf(y, c4.y, z * c4.z));
        s = __builtin_fmaf(er[4], d, s);
        d = __builtin_fmaf(x, c4.w, __builtin_fmaf(y, c8.x, z * c8.y));
        s = __builtin_fmaf(er[5], d, s);
        d = __builtin_fmaf(x, c8.z, __builtin_fmaf(y, c8.w, z * cc.x));
        s = __builtin_fmaf(er[6], d, s);
        // l=2 monomial basis with SH constants folded (shared by both orbitals)
        const float u1 = S3 * (x * z);
        const float u2 = S3 * (x * y);
        const float q3 = __builtin_fmaf(-0.5f, xx + zz, yy);
        const float u4 = S3 * (y * z);
        const float u5 = HS3 * (zz - xx);
        d = __builtin_fmaf(u1, cc.y, __builtin_fmaf(u2, cc.z,
            __builtin_fmaf(q3, cc.w, __builtin_fmaf(u4, cg.x, u5 * cg.y))));
        s = __builtin_fmaf(er[7], d, s);
        d = __builtin_fmaf(u1, cg.z, __builtin_fmaf(u2, cg.w,
            __builtin_fmaf(q3, ck.x, __builtin_fmaf(u4, ck.y, u5 * cm))));
        s = __builtin_fmaf(er[8], d, s);
        acc += s;
    }

    // reduce across the SUB consecutive lanes of this probe
    acc += __shfl_xor(acc, 1, 64);
    acc += __shfl_xor(acc, 2, 64);
    acc += __shfl_xor(acc, 4, 64);

    if (alive && sub == 0) out[p] = acc;
}

extern "C" void kernel_launch(void* const* d_in, const int* in_sizes, int n_in,
                              void* d_out, int out_size, void* d_ws, size_t ws_size,
                              hipStream_t stream) {
    const float* probe  = (const float*)d_in[0];
    const float* atom   = (const float*)d_in[1];
    const int*   n_prb  = (const int*)d_in[2];
    const int*   n_atm  = (const int*)d_in[3];
    const float* coeffs = (const float*)d_in[4];
    const float* expos  = (const float*)d_in[5];
    float*       out    = (float*)d_out;

    const int bsz  = in_sizes[2];
    const int ptot = out_size;

    const long threads = (long)ptot * SUB;
    const int block = 256;
    const int grid = (int)((threads + block - 1) / block);
    gto_kernel<<<grid, block, 0, stream>>>(probe, atom, n_prb, n_atm, coeffs, expos, out, bsz, ptot);
}